// Round 1
// baseline (328.205 us; speedup 1.0000x reference)
//
#include <hip/hip_runtime.h>
#include <math.h>

// ---------------------------------------------------------------------------
// Restormer block, B=1 DIM=3 NC=512 HEADS=2 -> CT=768, NT=32, HID=6. f32 I/O.
//
// R14: k_mlp inner loop moved to f16 G + v_dot2_f32_f16 (2 MAC/instr via the
// zero-padded 4th tap), G storage halved (f16, [row][n][ci][dx0..2,0] 32B/n),
// loads/chunk 30->20, R regs 36->24 -> 5 waves/SIMD via launch_bounds(256,5).
// k_attn (fused QK->softmax->PV) and k_ffn unchanged from R13.
// ---------------------------------------------------------------------------

__device__ __forceinline__ float sigm(float s) {
    return __builtin_amdgcn_rcpf(1.f + __expf(-s));
}

using bf16x8 = __attribute__((ext_vector_type(8))) short;   // 8 bf16 (4 VGPRs)
using f32x16 = __attribute__((ext_vector_type(16))) float;
using half2v = __attribute__((ext_vector_type(2))) _Float16;

__device__ __forceinline__ unsigned short f2bf(float f) {
    union { __bf16 h; unsigned short s; } u;
    u.h = (__bf16)f;                    // HW cvt, RNE
    return u.s;
}
__device__ __forceinline__ unsigned short f2h(float f) {
    union { _Float16 h; unsigned short s; } u;
    u.h = (_Float16)f;                  // HW cvt, RNE
    return u.s;
}
__device__ __forceinline__ half2v u2h2(unsigned int x) {
    union { unsigned int u; half2v h; } c; c.u = x; return c.h;
}
__device__ __forceinline__ half2v mkh2(float x, float y) {
    half2v r; r[0] = (_Float16)x; r[1] = (_Float16)y; return r;
}

#if __has_builtin(__builtin_amdgcn_fdot2)
__device__ __forceinline__ float fdot2(half2v a, half2v b, float c) {
    return __builtin_amdgcn_fdot2(a, b, c, false);
}
#else
__device__ __forceinline__ float fdot2(half2v a, half2v b, float c) {
    return fmaf((float)a[0], (float)b[0], fmaf((float)a[1], (float)b[1], c));
}
#endif

// ---- f32 workspace layout (element offsets) -------------------------------
// G is f16 now: per v, 515 rows x 32 n x 16 halves (32B per n; halves
// [ci*4+0..2] = dx taps, [ci*4+3] = 0, [12..15] unused). Rows 0,513,514 zero.
static constexpr int OFF_G   = 0;
static constexpr int GSTRIDE = 131840;    // floats per v: 515 * 256
static constexpr int OFF_S1  = 395520;    // [3v][32] column sums of w1
static constexpr int OFF_QKV = 395648;    // ushort: Qb[4][768][256] | Kb | Vt[4][256][768]
static constexpr int OFF_SC  = 1575296;   // w2 bf16 B-frag pack [3v][32hc][64lane][uint4]
static constexpr int OFF_ATT = 1599872;   // [4head][768][256] f32 == (3,512,512) flat
// total 2386304 floats = 9.5 MB

struct MlpPtrs {
    const float* b1[3];
    const float* w2[3];
    const float* b2[3];
};

// ---------------------------------------------------------------------------
// k_prep: zero G pad rows; S1[v][n] = sum_u w1v[u][n]; pack w2 into bf16
// B-fragments at OFF_SC.
// ---------------------------------------------------------------------------
__global__ __launch_bounds__(256) void k_prep(const float* __restrict__ qw1,
                                              const float* __restrict__ kw1,
                                              const float* __restrict__ vw1,
                                              MlpPtrs mp,
                                              float* __restrict__ ws) {
    int i = blockIdx.x * 256 + threadIdx.x;
    if (i < 2304) {                        // zero G pad rows 0,513,514 per v
        int v = i / 768, rr = (i % 768) / 256, col = i % 256;
        int row = (rr == 0) ? 0 : (512 + rr);
        ws[OFF_G + v * GSTRIDE + row * 256 + col] = 0.f;
    } else if (i >= 3584 && i < 9728) {    // S1: 96 waves, shuffle-reduce
        int j = i - 3584;
        int w = j >> 6, lane = j & 63;
        int v = w >> 5, n = w & 31;
        const float* w1p = (v == 0) ? qw1 : ((v == 1) ? kw1 : vw1);
        float s = 0.f;
#pragma unroll
        for (int k = 0; k < 8; k++) s += w1p[(lane + 64 * k) * 32 + n];
#pragma unroll
        for (int off = 32; off > 0; off >>= 1) s += __shfl_xor(s, off);
        if (lane == 0) ws[OFF_S1 + w] = s;
    } else if (i >= 9728 && i < 9728 + 6144) {   // w2 -> bf16 B-fragments
        int j = i - 9728;                  // j = v*2048 + hc*64 + lane
        int v = j >> 11, r = j & 2047;
        int hc = r >> 6, lane = r & 63;
        int o = lane & 31, half = lane >> 5;
        int H = hc * 16 + half * 8;
        const float* w2p = mp.w2[v];
        unsigned int d[4];
#pragma unroll
        for (int t = 0; t < 4; t++) {
            unsigned int lo = f2bf(w2p[(H + 2 * t) * 32 + o]);
            unsigned int hi = f2bf(w2p[(H + 2 * t + 1) * 32 + o]);
            d[t] = (hi << 16) | lo;
        }
        uint4* dst = (uint4*)(ws + OFF_SC);
        dst[j] = make_uint4(d[0], d[1], d[2], d[3]);
    }
}

// ---------------------------------------------------------------------------
// k_corr: G[v][h+1][n][ci][dx] = sum_u x[ci][h][u] * w1v[u+1-dx][n], f16 pack
// (a0,a1,a2,0) per (n,ci). grid (64 hblk, 3 ci, 3 v), block 256 = 8 rows x 32 n.
// ---------------------------------------------------------------------------
__global__ __launch_bounds__(256) void k_corr(const float* __restrict__ x,
                                              const float* __restrict__ qw1,
                                              const float* __restrict__ kw1,
                                              const float* __restrict__ vw1,
                                              float* __restrict__ ws) {
    const int h0 = blockIdx.x * 8, ci = blockIdx.y, v = blockIdx.z;
    const int tid = threadIdx.x;
    __shared__ __align__(16) float ws1t[32 * 516];

    const float* w1f = (v == 0) ? qw1 : ((v == 1) ? kw1 : vw1);
    for (int i = tid; i < 4096; i += 256) {       // transpose-stage w1
        int n_ = i & 31, u = (i >> 5) * 4;
        float a = w1f[(u + 0) * 32 + n_];
        float b = w1f[(u + 1) * 32 + n_];
        float c = w1f[(u + 2) * 32 + n_];
        float d = w1f[(u + 3) * 32 + n_];
        *(float4*)&ws1t[n_ * 516 + u] = make_float4(a, b, c, d);
    }
    if (tid < 32) *(float4*)&ws1t[tid * 516 + 512] = make_float4(0.f, 0.f, 0.f, 0.f);
    __syncthreads();

    const int hp = tid >> 5, n = tid & 31;
    const float* xrow = x + ci * 262144 + (h0 + hp) * 512;
    float a0 = 0.f, a1 = 0.f, a2 = 0.f, pq = 0.f;
    float4 cq = *(float4*)&ws1t[n * 516];
#pragma unroll 4
    for (int k = 0; k < 128; k++) {
        float4 nq = *(float4*)&ws1t[n * 516 + 4 * k + 4];
        float4 x4 = *(const float4*)&xrow[4 * k];
        a1 = fmaf(x4.x, cq.x, a1); a1 = fmaf(x4.y, cq.y, a1);
        a1 = fmaf(x4.z, cq.z, a1); a1 = fmaf(x4.w, cq.w, a1);
        a0 = fmaf(x4.x, cq.y, a0); a0 = fmaf(x4.y, cq.z, a0);
        a0 = fmaf(x4.z, cq.w, a0); a0 = fmaf(x4.w, nq.x, a0);
        a2 = fmaf(x4.x, pq,   a2); a2 = fmaf(x4.y, cq.x, a2);
        a2 = fmaf(x4.z, cq.y, a2); a2 = fmaf(x4.w, cq.z, a2);
        pq = cq.w; cq = nq;
    }
    unsigned int lo = ((unsigned int)f2h(a1) << 16) | f2h(a0);
    unsigned int hi = (unsigned int)f2h(a2);            // high half = 0
    char* gb = (char*)ws + (size_t)(OFF_G + v * GSTRIDE) * 4
             + (size_t)(h0 + hp + 1) * 1024 + n * 32 + ci * 8;
    *(uint2*)gb = make_uint2(lo, hi);
}

// ---------------------------------------------------------------------------
// k_mlp: block 256 thr = 4 ks-waves, same c-pair. f16 G rows, v_dot2_f32_f16
// 27-tap contraction (18 dot2 per (c,h)), rolling register tap rows shared by
// 2 c's, pre-packed w2 B-fragments, 2 MFMAs per chunk. LDS only for the final
// reduction. Epilogue writes bf16 Q,K and V^T.
// ---------------------------------------------------------------------------
__global__ __launch_bounds__(256, 5) void k_mlp(const float* __restrict__ cwp,
                                                const float* __restrict__ cbp,
                                                MlpPtrs mp, float* __restrict__ ws) {
    const int v = blockIdx.y;
    const int tid = threadIdx.x;
    const int ks = tid >> 6, lane = tid & 63;
    const int c0 = blockIdx.x * 2, c1 = c0 + 1;
    const int n = lane & 31;               // A-row (n-dim) AND B-col (o)
    const int half = lane >> 5;
    __shared__ float red[3][2][16][64];    // 24 KB: ks 1..3 -> epilogue wave

    const char* gvb = (const char*)ws + (size_t)(OFF_G + v * GSTRIDE) * 4;
    const uint4* w2pk = (const uint4*)(ws + OFF_SC) + (size_t)v * 2048 + lane;

    half2v cwa[3][3][2], cwb[3][3][2];     // [dy][ci][pair]; pair1 = (dx2, 0)
#pragma unroll
    for (int dy = 0; dy < 3; dy++)
#pragma unroll
        for (int ci = 0; ci < 3; ci++) {
            const float* p0 = cwp + c0 * 27 + ci * 9 + dy * 3;
            const float* p1 = cwp + c1 * 27 + ci * 9 + dy * 3;
            cwa[dy][ci][0] = mkh2(p0[0], p0[1]);
            cwa[dy][ci][1] = mkh2(p0[2], 0.f);
            cwb[dy][ci][0] = mkh2(p1[0], p1[1]);
            cwb[dy][ci][1] = mkh2(p1[2], 0.f);
        }
    const float s1v = ws[OFF_S1 + v * 32 + n];
    const float b1v = mp.b1[v][n];
    const float base0 = b1v + cbp[c0] * s1v;
    const float base1 = b1v + cbp[c1] * s1v;

    f32x16 acc0, acc1;
#pragma unroll
    for (int r = 0; r < 16; r++) { acc0[r] = 0.f; acc1[r] = 0.f; }

    for (int hcl = 0; hcl < 8; hcl++) {
        const int hc = ks * 8 + hcl;
        const int H = hc * 16 + half * 8;          // this lane's first h
        const char* rp = gvb + (size_t)H * 1024 + n * 32;

        union { uint4 u; bf16x8 b; } bw;           // shared B fragment
        bw.u = w2pk[hc * 64];

        half2v R[4][6];                            // rolling tap rows (f16 pairs)
#pragma unroll
        for (int s = 0; s < 4; s++) {
            uint4 ta = *(const uint4*)(rp + s * 1024);
            uint2 tb = *(const uint2*)(rp + s * 1024 + 16);
            R[s][0] = u2h2(ta.x); R[s][1] = u2h2(ta.y);
            R[s][2] = u2h2(ta.z); R[s][3] = u2h2(ta.w);
            R[s][4] = u2h2(tb.x); R[s][5] = u2h2(tb.y);
        }

        bf16x8 af0, af1;
#pragma unroll
        for (int j = 0; j < 8; j++) {
            float a0 = base0, a1 = 0.f, a2 = 0.f;
            float b0 = base1, b1 = 0.f, b2 = 0.f;
#pragma unroll
            for (int ci = 0; ci < 3; ci++) {
                half2v r00 = R[(j + 0) & 3][2 * ci], r01 = R[(j + 0) & 3][2 * ci + 1];
                half2v r10 = R[(j + 1) & 3][2 * ci], r11 = R[(j + 1) & 3][2 * ci + 1];
                half2v r20 = R[(j + 2) & 3][2 * ci], r21 = R[(j + 2) & 3][2 * ci + 1];
                a0 = fdot2(cwa[0][ci][0], r00, a0); a0 = fdot2(cwa[0][ci][1], r01, a0);
                a1 = fdot2(cwa[1][ci][0], r10, a1); a1 = fdot2(cwa[1][ci][1], r11, a1);
                a2 = fdot2(cwa[2][ci][0], r20, a2); a2 = fdot2(cwa[2][ci][1], r21, a2);
                b0 = fdot2(cwb[0][ci][0], r00, b0); b0 = fdot2(cwb[0][ci][1], r01, b0);
                b1 = fdot2(cwb[1][ci][0], r10, b1); b1 = fdot2(cwb[1][ci][1], r11, b1);
                b2 = fdot2(cwb[2][ci][0], r20, b2); b2 = fdot2(cwb[2][ci][1], r21, b2);
            }
            if (j < 6) {                   // refill slot j&3 with row H+j+4 (<=513)
                const char* q4 = rp + (size_t)(j + 4) * 1024;
                uint4 ta = *(const uint4*)(q4);
                uint2 tb = *(const uint2*)(q4 + 16);
                R[j & 3][0] = u2h2(ta.x); R[j & 3][1] = u2h2(ta.y);
                R[j & 3][2] = u2h2(ta.z); R[j & 3][3] = u2h2(ta.w);
                R[j & 3][4] = u2h2(tb.x); R[j & 3][5] = u2h2(tb.y);
            }
            af0[j] = (short)f2bf(sigm((a0 + a1) + a2));
            af1[j] = (short)f2bf(sigm((b0 + b1) + b2));
        }
        acc0 = __builtin_amdgcn_mfma_f32_32x32x16_bf16(af0, bw.b, acc0, 0, 0, 0);
        acc1 = __builtin_amdgcn_mfma_f32_32x32x16_bf16(af1, bw.b, acc1, 0, 0, 0);
    }

    if (ks > 0) {
#pragma unroll
        for (int r = 0; r < 16; r++) {
            red[ks - 1][0][r][lane] = acc0[r];
            red[ks - 1][1][r][lane] = acc1[r];
        }
    }
    __syncthreads();
    if (ks == 0) {
        const float b2v = mp.b2[v][n];      // o == lane&31
        unsigned short* uq = (unsigned short*)(ws + OFF_QKV);
#pragma unroll
        for (int cc = 0; cc < 2; cc++) {
            const int c = c0 + cc;
#pragma unroll
            for (int r = 0; r < 16; r++) {
                float a = (cc == 0 ? acc0[r] : acc1[r])
                        + red[0][cc][r][lane] + red[1][cc][r][lane] + red[2][cc][r][lane];
                int nn = (r & 3) + 8 * (r >> 2) + 4 * half;   // n-dim (row)
                float m = sigm(a + b2v);
                int head = ((n & 1) << 1) | (nn & 1);
                int sidx = ((n >> 1) << 4) | (nn >> 1);
                if (v < 2)  uq[v * 786432 + head * 196608 + c * 256 + sidx] = f2bf(m);
                else        uq[2 * 786432 + head * 196608 + sidx * 768 + c] = f2bf(m);
            }
        }
    }
}

// ---------------------------------------------------------------------------
// k_attn: fused QK^T * temp -> softmax -> @V for one (head, 32-row band).
// Block 512 = 8 waves. Phase 1: wave w computes j-tiles w*3..w*3+2 (scores
// in 3 f32x16 regs). Phase 2: block softmax — m-lane shuffle reduce, tiny
// LDS cross-wave max/sum. Phase 3: attn bf16 -> LDS (pitch 776), wave w
// computes output s-tile w via MFMA with A-frags from LDS, V^T from L2.
// grid (24 iband, 4 head).
// ---------------------------------------------------------------------------
__global__ __launch_bounds__(512) void k_attn(const float* __restrict__ tempr,
                                              float* __restrict__ ws) {
    const unsigned short* uq = (const unsigned short*)(ws + OFF_QKV);
    const int head = blockIdx.y;
    const int i0 = blockIdx.x * 32;
    const int w = threadIdx.x >> 6, lane = threadIdx.x & 63;
    const int m = lane & 31, half = lane >> 5;

    __shared__ __align__(16) unsigned short ap[32][776];   // attn bf16, padded
    __shared__ float mxw[8][32];
    __shared__ float smw[8][32];
    __shared__ float gmx[32];
    __shared__ float gsm[32];

    const float temp = tempr[head];
    const unsigned short* Qp = uq + head * 196608 + (i0 + m) * 256 + half * 8;

    // ---- phase 1: QK^T for 3 j-tiles --------------------------------------
    f32x16 acc[3];
#pragma unroll
    for (int t = 0; t < 3; t++)
#pragma unroll
        for (int r = 0; r < 16; r++) acc[t][r] = 0.f;
#pragma unroll
    for (int t = 0; t < 3; t++) {
        const int j0 = (w * 3 + t) * 32;
        const unsigned short* Kp = uq + 786432 + head * 196608 + (j0 + m) * 256 + half * 8;
#pragma unroll
        for (int kk = 0; kk < 16; kk++) {
            bf16x8 af = *(const bf16x8*)(Qp + kk * 16);
            bf16x8 bf = *(const bf16x8*)(Kp + kk * 16);
            acc[t] = __builtin_amdgcn_mfma_f32_32x32x16_bf16(af, bf, acc[t], 0, 0, 0);
        }
    }
    // scale by temperature (before max: temp sign matters in general)
#pragma unroll
    for (int t = 0; t < 3; t++)
#pragma unroll
        for (int r = 0; r < 16; r++) acc[t][r] *= temp;

    // ---- phase 2: block softmax -------------------------------------------
    int rowv[16];
#pragma unroll
    for (int r = 0; r < 16; r++) rowv[r] = (r & 3) + 8 * (r >> 2) + 4 * half;

    float rmx[16];
#pragma unroll
    for (int r = 0; r < 16; r++)
        rmx[r] = fmaxf(fmaxf(acc[0][r], acc[1][r]), acc[2][r]);
#pragma unroll
    for (int off = 16; off > 0; off >>= 1)
#pragma unroll
        for (int r = 0; r < 16; r++) rmx[r] = fmaxf(rmx[r], __shfl_xor(rmx[r], off));
    if (m == 0) {
#pragma unroll
        for (int r = 0; r < 16; r++) mxw[w][rowv[r]] = rmx[r];
    }
    __syncthreads();
    if (threadIdx.x < 32) {
        float g = mxw[0][threadIdx.x];
#pragma unroll
        for (int ww = 1; ww < 8; ww++) g = fmaxf(g, mxw[ww][threadIdx.x]);
        gmx[threadIdx.x] = g;
    }
    __syncthreads();

    float rsm[16];
#pragma unroll
    for (int r = 0; r < 16; r++) {
        float gm = gmx[rowv[r]];
        float e0 = __expf(acc[0][r] - gm);
        float e1 = __expf(acc[1][r] - gm);
        float e2 = __expf(acc[2][r] - gm);
        acc[0][r] = e0; acc[1][r] = e1; acc[2][r] = e2;
        rsm[r] = (e0 + e1) + e2;
    }
#pragma unroll
    for (int off = 16; off > 0; off >>= 1)
#pragma unroll
        for (int r = 0; r < 16; r++) rsm[r] += __shfl_xor(rsm[r], off);
    if (m == 0) {
#pragma unroll
        for (int r = 0; r < 16; r++) smw[w][rowv[r]] = rsm[r];
    }
    __syncthreads();
    if (threadIdx.x < 32) {
        float g = smw[0][threadIdx.x];
#pragma unroll
        for (int ww = 1; ww < 8; ww++) g += smw[ww][threadIdx.x];
        gsm[threadIdx.x] = g;
    }
    __syncthreads();

    // ---- phase 3: attn bf16 -> LDS, then PV --------------------------------
#pragma unroll
    for (int r = 0; r < 16; r++) {
        float inv = __builtin_amdgcn_rcpf(gsm[rowv[r]]);
#pragma unroll
        for (int t = 0; t < 3; t++)
            ap[rowv[r]][(w * 3 + t) * 32 + m] = f2bf(acc[t][r] * inv);
    }
    __syncthreads();

    const int s0 = w * 32;
    const unsigned short* Vp = uq + 2 * 786432 + head * 196608 + (s0 + m) * 768 + half * 8;
    f32x16 po;
#pragma unroll
    for (int r = 0; r < 16; r++) po[r] = 0.f;
#pragma unroll
    for (int kk = 0; kk < 48; kk++) {
        bf16x8 af = *(const bf16x8*)&ap[m][half * 8 + kk * 16];
        bf16x8 bf = *(const bf16x8*)(Vp + kk * 16);
        po = __builtin_amdgcn_mfma_f32_32x32x16_bf16(af, bf, po, 0, 0, 0);
    }
    float* O = ws + OFF_ATT + head * 196608;
#pragma unroll
    for (int r = 0; r < 16; r++) {
        O[(i0 + rowv[r]) * 256 + s0 + m] = po[r];
    }
}

// ---------------------------------------------------------------------------
// k_ffn: fused pointwise(3->12) + dwconv3x3 + gelu-gate + pointwise(6->3)
// + residual, f32 store. 32x16 pixel tiles (512 blocks), 34x18 halo in LDS.
// ---------------------------------------------------------------------------
struct FfnPtrs { const float* p[6]; };  // pi_w, pi_b, dw_w, dw_b, po_w, po_b

__global__ __launch_bounds__(256) void k_ffn(const float* __restrict__ ws,
                                             const float* __restrict__ x,
                                             FfnPtrs fp,
                                             float* __restrict__ out) {
    const int x0 = blockIdx.x * 32, y0 = blockIdx.y * 16;
    __shared__ float wsm[192];
    __shared__ float p[12][612];
    const int tid = threadIdx.x;
    if (tid < 36)       wsm[tid] = fp.p[0][tid];          // pi_w (12,3)
    else if (tid < 48)  wsm[tid] = fp.p[1][tid - 36];     // pi_b (12)
    else if (tid < 156) wsm[tid] = fp.p[2][tid - 48];     // dw_w (12,9)
    else if (tid < 168) wsm[tid] = fp.p[3][tid - 156];    // dw_b (12)
    else if (tid < 186) wsm[tid] = fp.p[4][tid - 168];    // po_w (3,6)
    else if (tid < 189) wsm[tid] = fp.p[5][tid - 186];    // po_b (3)
    __syncthreads();

    const float* A = ws + OFF_ATT;
    for (int i = tid; i < 612; i += 256) {
        int py = i / 34, px = i % 34;
        int gy = y0 + py - 1, gx = x0 + px - 1;
        bool in = ((unsigned)gy < 512u) && ((unsigned)gx < 512u);
        float a0 = 0.f, a1 = 0.f, a2 = 0.f;
        if (in) {
            int b = gy * 512 + gx;
            a0 = A[b]; a1 = A[262144 + b]; a2 = A[524288 + b];
        }
#pragma unroll
        for (int j = 0; j < 12; j++) {
            float t = in ? (wsm[36 + j] + wsm[j * 3] * a0 + wsm[j * 3 + 1] * a1
                            + wsm[j * 3 + 2] * a2)
                         : 0.f;
            p[j][i] = t;
        }
    }
    __syncthreads();

#pragma unroll
    for (int it = 0; it < 2; it++) {
        int pl = tid + it * 256;
        int ly = pl >> 5, lx = pl & 31;
        float z[12];
#pragma unroll
        for (int j = 0; j < 12; j++) {
            const float* dw = &wsm[48 + j * 9];
            const float* pr = &p[j][ly * 34 + lx];
            z[j] = wsm[156 + j]
                 + dw[0] * pr[0]  + dw[1] * pr[1]  + dw[2] * pr[2]
                 + dw[3] * pr[34] + dw[4] * pr[35] + dw[5] * pr[36]
                 + dw[6] * pr[68] + dw[7] * pr[69] + dw[8] * pr[70];
        }
        float g[6];
#pragma unroll
        for (int j = 0; j < 6; j++) {
            float xx = z[j];
            g[j] = 0.5f * xx * (1.f + erff(xx * 0.70710678118f)) * z[6 + j];
        }
        int b = (y0 + ly) * 512 + (x0 + lx);
#pragma unroll
        for (int co = 0; co < 3; co++) {
            float r = wsm[186 + co];
#pragma unroll
            for (int j = 0; j < 6; j++) r = fmaf(wsm[168 + co * 6 + j], g[j], r);
            r += x[co * 262144 + b];             // residual
            out[co * 262144 + b] = r;
        }
    }
}

// ---------------------------------------------------------------------------
extern "C" void kernel_launch(void* const* d_in, const int* in_sizes, int n_in,
                              void* d_out, int out_size, void* d_ws, size_t ws_size,
                              hipStream_t stream) {
    float* ws = (float*)d_ws;
    float* out = (float*)d_out;
    const float* x   = (const float*)d_in[0];
    const float* cw  = (const float*)d_in[1];
    const float* cb  = (const float*)d_in[2];
    const float* qw1 = (const float*)d_in[3];
    const float* kw1 = (const float*)d_in[7];
    const float* vw1 = (const float*)d_in[11];
    const float* temp= (const float*)d_in[15];

    MlpPtrs mp;
    mp.b1[0] = (const float*)d_in[4];  mp.w2[0] = (const float*)d_in[5];  mp.b2[0] = (const float*)d_in[6];
    mp.b1[1] = (const float*)d_in[8];  mp.w2[1] = (const float*)d_in[9];  mp.b2[1] = (const float*)d_in[10];
    mp.b1[2] = (const float*)d_in[12]; mp.w2[2] = (const float*)d_in[13]; mp.b2[2] = (const float*)d_in[14];

    FfnPtrs fp;
    for (int i = 0; i < 6; i++) fp.p[i] = (const float*)d_in[16 + i];

    k_prep<<<62, 256, 0, stream>>>(qw1, kw1, vw1, mp, ws);
    k_corr<<<dim3(64, 3, 3), 256, 0, stream>>>(x, qw1, kw1, vw1, ws);
    k_mlp <<<dim3(384, 3), 256, 0, stream>>>(cw, cb, mp, ws);
    k_attn<<<dim3(24, 4), 512, 0, stream>>>(temp, ws);
    k_ffn <<<dim3(16, 32), 256, 0, stream>>>(ws, x, fp, out);
}

// Round 2
// 221.929 us; speedup vs baseline: 1.4789x; 1.4789x over previous
//
#include <hip/hip_runtime.h>
#include <math.h>

// ---------------------------------------------------------------------------
// Restormer block, B=1 DIM=3 NC=512 HEADS=2 -> CT=768, NT=32, HID=6. f32 I/O.
//
// R15: R14's f16-G + v_dot2_f32_f16 k_mlp, but WITHOUT the forced
// launch_bounds(256,5) occupancy pragma that made the allocator spill the
// MFMA accumulators to scratch (WRITE_SIZE 15MB -> 243MB in R14's counters).
// Natural allocation (~100 VGPR) keeps acc/R/cw in registers.
// k_attn (fused QK->softmax->PV) and k_ffn unchanged from R13.
// ---------------------------------------------------------------------------

__device__ __forceinline__ float sigm(float s) {
    return __builtin_amdgcn_rcpf(1.f + __expf(-s));
}

using bf16x8 = __attribute__((ext_vector_type(8))) short;   // 8 bf16 (4 VGPRs)
using f32x16 = __attribute__((ext_vector_type(16))) float;
using half2v = __attribute__((ext_vector_type(2))) _Float16;

__device__ __forceinline__ unsigned short f2bf(float f) {
    union { __bf16 h; unsigned short s; } u;
    u.h = (__bf16)f;                    // HW cvt, RNE
    return u.s;
}
__device__ __forceinline__ unsigned short f2h(float f) {
    union { _Float16 h; unsigned short s; } u;
    u.h = (_Float16)f;                  // HW cvt, RNE
    return u.s;
}
__device__ __forceinline__ half2v u2h2(unsigned int x) {
    union { unsigned int u; half2v h; } c; c.u = x; return c.h;
}
__device__ __forceinline__ half2v mkh2(float x, float y) {
    half2v r; r[0] = (_Float16)x; r[1] = (_Float16)y; return r;
}

#if __has_builtin(__builtin_amdgcn_fdot2)
__device__ __forceinline__ float fdot2(half2v a, half2v b, float c) {
    return __builtin_amdgcn_fdot2(a, b, c, false);
}
#else
__device__ __forceinline__ float fdot2(half2v a, half2v b, float c) {
    return fmaf((float)a[0], (float)b[0], fmaf((float)a[1], (float)b[1], c));
}
#endif

// ---- f32 workspace layout (element offsets) -------------------------------
// G is f16: per v, 515 rows x 32 n x 16 halves (32B per n; halves
// [ci*4+0..2] = dx taps, [ci*4+3] = 0, [12..15] unused). Rows 0,513,514 zero.
static constexpr int OFF_G   = 0;
static constexpr int GSTRIDE = 131840;    // floats per v: 515 * 256
static constexpr int OFF_S1  = 395520;    // [3v][32] column sums of w1
static constexpr int OFF_QKV = 395648;    // ushort: Qb[4][768][256] | Kb | Vt[4][256][768]
static constexpr int OFF_SC  = 1575296;   // w2 bf16 B-frag pack [3v][32hc][64lane][uint4]
static constexpr int OFF_ATT = 1599872;   // [4head][768][256] f32 == (3,512,512) flat
// total 2386304 floats = 9.5 MB

struct MlpPtrs {
    const float* b1[3];
    const float* w2[3];
    const float* b2[3];
};

// ---------------------------------------------------------------------------
// k_prep: zero G pad rows; S1[v][n] = sum_u w1v[u][n]; pack w2 into bf16
// B-fragments at OFF_SC.
// ---------------------------------------------------------------------------
__global__ __launch_bounds__(256) void k_prep(const float* __restrict__ qw1,
                                              const float* __restrict__ kw1,
                                              const float* __restrict__ vw1,
                                              MlpPtrs mp,
                                              float* __restrict__ ws) {
    int i = blockIdx.x * 256 + threadIdx.x;
    if (i < 2304) {                        // zero G pad rows 0,513,514 per v
        int v = i / 768, rr = (i % 768) / 256, col = i % 256;
        int row = (rr == 0) ? 0 : (512 + rr);
        ws[OFF_G + v * GSTRIDE + row * 256 + col] = 0.f;
    } else if (i >= 3584 && i < 9728) {    // S1: 96 waves, shuffle-reduce
        int j = i - 3584;
        int w = j >> 6, lane = j & 63;
        int v = w >> 5, n = w & 31;
        const float* w1p = (v == 0) ? qw1 : ((v == 1) ? kw1 : vw1);
        float s = 0.f;
#pragma unroll
        for (int k = 0; k < 8; k++) s += w1p[(lane + 64 * k) * 32 + n];
#pragma unroll
        for (int off = 32; off > 0; off >>= 1) s += __shfl_xor(s, off);
        if (lane == 0) ws[OFF_S1 + w] = s;
    } else if (i >= 9728 && i < 9728 + 6144) {   // w2 -> bf16 B-fragments
        int j = i - 9728;                  // j = v*2048 + hc*64 + lane
        int v = j >> 11, r = j & 2047;
        int hc = r >> 6, lane = r & 63;
        int o = lane & 31, half = lane >> 5;
        int H = hc * 16 + half * 8;
        const float* w2p = mp.w2[v];
        unsigned int d[4];
#pragma unroll
        for (int t = 0; t < 4; t++) {
            unsigned int lo = f2bf(w2p[(H + 2 * t) * 32 + o]);
            unsigned int hi = f2bf(w2p[(H + 2 * t + 1) * 32 + o]);
            d[t] = (hi << 16) | lo;
        }
        uint4* dst = (uint4*)(ws + OFF_SC);
        dst[j] = make_uint4(d[0], d[1], d[2], d[3]);
    }
}

// ---------------------------------------------------------------------------
// k_corr: G[v][h+1][n][ci][dx] = sum_u x[ci][h][u] * w1v[u+1-dx][n], f16 pack
// (a0,a1,a2,0) per (n,ci). grid (64 hblk, 3 ci, 3 v), block 256 = 8 rows x 32 n.
// ---------------------------------------------------------------------------
__global__ __launch_bounds__(256) void k_corr(const float* __restrict__ x,
                                              const float* __restrict__ qw1,
                                              const float* __restrict__ kw1,
                                              const float* __restrict__ vw1,
                                              float* __restrict__ ws) {
    const int h0 = blockIdx.x * 8, ci = blockIdx.y, v = blockIdx.z;
    const int tid = threadIdx.x;
    __shared__ __align__(16) float ws1t[32 * 516];

    const float* w1f = (v == 0) ? qw1 : ((v == 1) ? kw1 : vw1);
    for (int i = tid; i < 4096; i += 256) {       // transpose-stage w1
        int n_ = i & 31, u = (i >> 5) * 4;
        float a = w1f[(u + 0) * 32 + n_];
        float b = w1f[(u + 1) * 32 + n_];
        float c = w1f[(u + 2) * 32 + n_];
        float d = w1f[(u + 3) * 32 + n_];
        *(float4*)&ws1t[n_ * 516 + u] = make_float4(a, b, c, d);
    }
    if (tid < 32) *(float4*)&ws1t[tid * 516 + 512] = make_float4(0.f, 0.f, 0.f, 0.f);
    __syncthreads();

    const int hp = tid >> 5, n = tid & 31;
    const float* xrow = x + ci * 262144 + (h0 + hp) * 512;
    float a0 = 0.f, a1 = 0.f, a2 = 0.f, pq = 0.f;
    float4 cq = *(float4*)&ws1t[n * 516];
#pragma unroll 4
    for (int k = 0; k < 128; k++) {
        float4 nq = *(float4*)&ws1t[n * 516 + 4 * k + 4];
        float4 x4 = *(const float4*)&xrow[4 * k];
        a1 = fmaf(x4.x, cq.x, a1); a1 = fmaf(x4.y, cq.y, a1);
        a1 = fmaf(x4.z, cq.z, a1); a1 = fmaf(x4.w, cq.w, a1);
        a0 = fmaf(x4.x, cq.y, a0); a0 = fmaf(x4.y, cq.z, a0);
        a0 = fmaf(x4.z, cq.w, a0); a0 = fmaf(x4.w, nq.x, a0);
        a2 = fmaf(x4.x, pq,   a2); a2 = fmaf(x4.y, cq.x, a2);
        a2 = fmaf(x4.z, cq.y, a2); a2 = fmaf(x4.w, cq.z, a2);
        pq = cq.w; cq = nq;
    }
    unsigned int lo = ((unsigned int)f2h(a1) << 16) | f2h(a0);
    unsigned int hi = (unsigned int)f2h(a2);            // high half = 0
    char* gb = (char*)ws + (size_t)(OFF_G + v * GSTRIDE) * 4
             + (size_t)(h0 + hp + 1) * 1024 + n * 32 + ci * 8;
    *(uint2*)gb = make_uint2(lo, hi);
}

// ---------------------------------------------------------------------------
// k_mlp: block 256 thr = 4 ks-waves, same c-pair. f16 G rows, v_dot2_f32_f16
// 27-tap contraction (18 dot2 per (c,h)), rolling register tap rows shared by
// 2 c's, pre-packed w2 B-fragments, 2 MFMAs per chunk. LDS only for the final
// reduction. Epilogue writes bf16 Q,K and V^T. Natural occupancy (no forced
// min-waves: R14's (256,5) spilled the accumulators -> 243MB scratch writes).
// ---------------------------------------------------------------------------
__global__ __launch_bounds__(256) void k_mlp(const float* __restrict__ cwp,
                                             const float* __restrict__ cbp,
                                             MlpPtrs mp, float* __restrict__ ws) {
    const int v = blockIdx.y;
    const int tid = threadIdx.x;
    const int ks = tid >> 6, lane = tid & 63;
    const int c0 = blockIdx.x * 2, c1 = c0 + 1;
    const int n = lane & 31;               // A-row (n-dim) AND B-col (o)
    const int half = lane >> 5;
    __shared__ float red[3][2][16][64];    // 24 KB: ks 1..3 -> epilogue wave

    const char* gvb = (const char*)ws + (size_t)(OFF_G + v * GSTRIDE) * 4;
    const uint4* w2pk = (const uint4*)(ws + OFF_SC) + (size_t)v * 2048 + lane;

    half2v cwa[3][3][2], cwb[3][3][2];     // [dy][ci][pair]; pair1 = (dx2, 0)
#pragma unroll
    for (int dy = 0; dy < 3; dy++)
#pragma unroll
        for (int ci = 0; ci < 3; ci++) {
            const float* p0 = cwp + c0 * 27 + ci * 9 + dy * 3;
            const float* p1 = cwp + c1 * 27 + ci * 9 + dy * 3;
            cwa[dy][ci][0] = mkh2(p0[0], p0[1]);
            cwa[dy][ci][1] = mkh2(p0[2], 0.f);
            cwb[dy][ci][0] = mkh2(p1[0], p1[1]);
            cwb[dy][ci][1] = mkh2(p1[2], 0.f);
        }
    const float s1v = ws[OFF_S1 + v * 32 + n];
    const float b1v = mp.b1[v][n];
    const float base0 = b1v + cbp[c0] * s1v;
    const float base1 = b1v + cbp[c1] * s1v;

    f32x16 acc0, acc1;
#pragma unroll
    for (int r = 0; r < 16; r++) { acc0[r] = 0.f; acc1[r] = 0.f; }

    for (int hcl = 0; hcl < 8; hcl++) {
        const int hc = ks * 8 + hcl;
        const int H = hc * 16 + half * 8;          // this lane's first h
        const char* rp = gvb + (size_t)H * 1024 + n * 32;

        union { uint4 u; bf16x8 b; } bw;           // shared B fragment
        bw.u = w2pk[hc * 64];

        half2v R[4][6];                            // rolling tap rows (f16 pairs)
#pragma unroll
        for (int s = 0; s < 4; s++) {
            uint4 ta = *(const uint4*)(rp + s * 1024);
            uint2 tb = *(const uint2*)(rp + s * 1024 + 16);
            R[s][0] = u2h2(ta.x); R[s][1] = u2h2(ta.y);
            R[s][2] = u2h2(ta.z); R[s][3] = u2h2(ta.w);
            R[s][4] = u2h2(tb.x); R[s][5] = u2h2(tb.y);
        }

        bf16x8 af0, af1;
#pragma unroll
        for (int j = 0; j < 8; j++) {
            float a0 = base0, a1 = 0.f, a2 = 0.f;
            float b0 = base1, b1 = 0.f, b2 = 0.f;
#pragma unroll
            for (int ci = 0; ci < 3; ci++) {
                half2v r00 = R[(j + 0) & 3][2 * ci], r01 = R[(j + 0) & 3][2 * ci + 1];
                half2v r10 = R[(j + 1) & 3][2 * ci], r11 = R[(j + 1) & 3][2 * ci + 1];
                half2v r20 = R[(j + 2) & 3][2 * ci], r21 = R[(j + 2) & 3][2 * ci + 1];
                a0 = fdot2(cwa[0][ci][0], r00, a0); a0 = fdot2(cwa[0][ci][1], r01, a0);
                a1 = fdot2(cwa[1][ci][0], r10, a1); a1 = fdot2(cwa[1][ci][1], r11, a1);
                a2 = fdot2(cwa[2][ci][0], r20, a2); a2 = fdot2(cwa[2][ci][1], r21, a2);
                b0 = fdot2(cwb[0][ci][0], r00, b0); b0 = fdot2(cwb[0][ci][1], r01, b0);
                b1 = fdot2(cwb[1][ci][0], r10, b1); b1 = fdot2(cwb[1][ci][1], r11, b1);
                b2 = fdot2(cwb[2][ci][0], r20, b2); b2 = fdot2(cwb[2][ci][1], r21, b2);
            }
            if (j < 6) {                   // refill slot j&3 with row H+j+4 (<=513)
                const char* q4 = rp + (size_t)(j + 4) * 1024;
                uint4 ta = *(const uint4*)(q4);
                uint2 tb = *(const uint2*)(q4 + 16);
                R[j & 3][0] = u2h2(ta.x); R[j & 3][1] = u2h2(ta.y);
                R[j & 3][2] = u2h2(ta.z); R[j & 3][3] = u2h2(ta.w);
                R[j & 3][4] = u2h2(tb.x); R[j & 3][5] = u2h2(tb.y);
            }
            af0[j] = (short)f2bf(sigm((a0 + a1) + a2));
            af1[j] = (short)f2bf(sigm((b0 + b1) + b2));
        }
        acc0 = __builtin_amdgcn_mfma_f32_32x32x16_bf16(af0, bw.b, acc0, 0, 0, 0);
        acc1 = __builtin_amdgcn_mfma_f32_32x32x16_bf16(af1, bw.b, acc1, 0, 0, 0);
    }

    if (ks > 0) {
#pragma unroll
        for (int r = 0; r < 16; r++) {
            red[ks - 1][0][r][lane] = acc0[r];
            red[ks - 1][1][r][lane] = acc1[r];
        }
    }
    __syncthreads();
    if (ks == 0) {
        const float b2v = mp.b2[v][n];      // o == lane&31
        unsigned short* uq = (unsigned short*)(ws + OFF_QKV);
#pragma unroll
        for (int cc = 0; cc < 2; cc++) {
            const int c = c0 + cc;
#pragma unroll
            for (int r = 0; r < 16; r++) {
                float a = (cc == 0 ? acc0[r] : acc1[r])
                        + red[0][cc][r][lane] + red[1][cc][r][lane] + red[2][cc][r][lane];
                int nn = (r & 3) + 8 * (r >> 2) + 4 * half;   // n-dim (row)
                float m = sigm(a + b2v);
                int head = ((n & 1) << 1) | (nn & 1);
                int sidx = ((n >> 1) << 4) | (nn >> 1);
                if (v < 2)  uq[v * 786432 + head * 196608 + c * 256 + sidx] = f2bf(m);
                else        uq[2 * 786432 + head * 196608 + sidx * 768 + c] = f2bf(m);
            }
        }
    }
}

// ---------------------------------------------------------------------------
// k_attn: fused QK^T * temp -> softmax -> @V for one (head, 32-row band).
// Block 512 = 8 waves. Phase 1: wave w computes j-tiles w*3..w*3+2 (scores
// in 3 f32x16 regs). Phase 2: block softmax — m-lane shuffle reduce, tiny
// LDS cross-wave max/sum. Phase 3: attn bf16 -> LDS (pitch 776), wave w
// computes output s-tile w via MFMA with A-frags from LDS, V^T from L2.
// grid (24 iband, 4 head).
// ---------------------------------------------------------------------------
__global__ __launch_bounds__(512) void k_attn(const float* __restrict__ tempr,
                                              float* __restrict__ ws) {
    const unsigned short* uq = (const unsigned short*)(ws + OFF_QKV);
    const int head = blockIdx.y;
    const int i0 = blockIdx.x * 32;
    const int w = threadIdx.x >> 6, lane = threadIdx.x & 63;
    const int m = lane & 31, half = lane >> 5;

    __shared__ __align__(16) unsigned short ap[32][776];   // attn bf16, padded
    __shared__ float mxw[8][32];
    __shared__ float smw[8][32];
    __shared__ float gmx[32];
    __shared__ float gsm[32];

    const float temp = tempr[head];
    const unsigned short* Qp = uq + head * 196608 + (i0 + m) * 256 + half * 8;

    // ---- phase 1: QK^T for 3 j-tiles --------------------------------------
    f32x16 acc[3];
#pragma unroll
    for (int t = 0; t < 3; t++)
#pragma unroll
        for (int r = 0; r < 16; r++) acc[t][r] = 0.f;
#pragma unroll
    for (int t = 0; t < 3; t++) {
        const int j0 = (w * 3 + t) * 32;
        const unsigned short* Kp = uq + 786432 + head * 196608 + (j0 + m) * 256 + half * 8;
#pragma unroll
        for (int kk = 0; kk < 16; kk++) {
            bf16x8 af = *(const bf16x8*)(Qp + kk * 16);
            bf16x8 bf = *(const bf16x8*)(Kp + kk * 16);
            acc[t] = __builtin_amdgcn_mfma_f32_32x32x16_bf16(af, bf, acc[t], 0, 0, 0);
        }
    }
    // scale by temperature (before max: temp sign matters in general)
#pragma unroll
    for (int t = 0; t < 3; t++)
#pragma unroll
        for (int r = 0; r < 16; r++) acc[t][r] *= temp;

    // ---- phase 2: block softmax -------------------------------------------
    int rowv[16];
#pragma unroll
    for (int r = 0; r < 16; r++) rowv[r] = (r & 3) + 8 * (r >> 2) + 4 * half;

    float rmx[16];
#pragma unroll
    for (int r = 0; r < 16; r++)
        rmx[r] = fmaxf(fmaxf(acc[0][r], acc[1][r]), acc[2][r]);
#pragma unroll
    for (int off = 16; off > 0; off >>= 1)
#pragma unroll
        for (int r = 0; r < 16; r++) rmx[r] = fmaxf(rmx[r], __shfl_xor(rmx[r], off));
    if (m == 0) {
#pragma unroll
        for (int r = 0; r < 16; r++) mxw[w][rowv[r]] = rmx[r];
    }
    __syncthreads();
    if (threadIdx.x < 32) {
        float g = mxw[0][threadIdx.x];
#pragma unroll
        for (int ww = 1; ww < 8; ww++) g = fmaxf(g, mxw[ww][threadIdx.x]);
        gmx[threadIdx.x] = g;
    }
    __syncthreads();

    float rsm[16];
#pragma unroll
    for (int r = 0; r < 16; r++) {
        float gm = gmx[rowv[r]];
        float e0 = __expf(acc[0][r] - gm);
        float e1 = __expf(acc[1][r] - gm);
        float e2 = __expf(acc[2][r] - gm);
        acc[0][r] = e0; acc[1][r] = e1; acc[2][r] = e2;
        rsm[r] = (e0 + e1) + e2;
    }
#pragma unroll
    for (int off = 16; off > 0; off >>= 1)
#pragma unroll
        for (int r = 0; r < 16; r++) rsm[r] += __shfl_xor(rsm[r], off);
    if (m == 0) {
#pragma unroll
        for (int r = 0; r < 16; r++) smw[w][rowv[r]] = rsm[r];
    }
    __syncthreads();
    if (threadIdx.x < 32) {
        float g = smw[0][threadIdx.x];
#pragma unroll
        for (int ww = 1; ww < 8; ww++) g += smw[ww][threadIdx.x];
        gsm[threadIdx.x] = g;
    }
    __syncthreads();

    // ---- phase 3: attn bf16 -> LDS, then PV --------------------------------
#pragma unroll
    for (int r = 0; r < 16; r++) {
        float inv = __builtin_amdgcn_rcpf(gsm[rowv[r]]);
#pragma unroll
        for (int t = 0; t < 3; t++)
            ap[rowv[r]][(w * 3 + t) * 32 + m] = f2bf(acc[t][r] * inv);
    }
    __syncthreads();

    const int s0 = w * 32;
    const unsigned short* Vp = uq + 2 * 786432 + head * 196608 + (s0 + m) * 768 + half * 8;
    f32x16 po;
#pragma unroll
    for (int r = 0; r < 16; r++) po[r] = 0.f;
#pragma unroll
    for (int kk = 0; kk < 48; kk++) {
        bf16x8 af = *(const bf16x8*)&ap[m][half * 8 + kk * 16];
        bf16x8 bf = *(const bf16x8*)(Vp + kk * 16);
        po = __builtin_amdgcn_mfma_f32_32x32x16_bf16(af, bf, po, 0, 0, 0);
    }
    float* O = ws + OFF_ATT + head * 196608;
#pragma unroll
    for (int r = 0; r < 16; r++) {
        O[(i0 + rowv[r]) * 256 + s0 + m] = po[r];
    }
}

// ---------------------------------------------------------------------------
// k_ffn: fused pointwise(3->12) + dwconv3x3 + gelu-gate + pointwise(6->3)
// + residual, f32 store. 32x16 pixel tiles (512 blocks), 34x18 halo in LDS.
// ---------------------------------------------------------------------------
struct FfnPtrs { const float* p[6]; };  // pi_w, pi_b, dw_w, dw_b, po_w, po_b

__global__ __launch_bounds__(256) void k_ffn(const float* __restrict__ ws,
                                             const float* __restrict__ x,
                                             FfnPtrs fp,
                                             float* __restrict__ out) {
    const int x0 = blockIdx.x * 32, y0 = blockIdx.y * 16;
    __shared__ float wsm[192];
    __shared__ float p[12][612];
    const int tid = threadIdx.x;
    if (tid < 36)       wsm[tid] = fp.p[0][tid];          // pi_w (12,3)
    else if (tid < 48)  wsm[tid] = fp.p[1][tid - 36];     // pi_b (12)
    else if (tid < 156) wsm[tid] = fp.p[2][tid - 48];     // dw_w (12,9)
    else if (tid < 168) wsm[tid] = fp.p[3][tid - 156];    // dw_b (12)
    else if (tid < 186) wsm[tid] = fp.p[4][tid - 168];    // po_w (3,6)
    else if (tid < 189) wsm[tid] = fp.p[5][tid - 186];    // po_b (3)
    __syncthreads();

    const float* A = ws + OFF_ATT;
    for (int i = tid; i < 612; i += 256) {
        int py = i / 34, px = i % 34;
        int gy = y0 + py - 1, gx = x0 + px - 1;
        bool in = ((unsigned)gy < 512u) && ((unsigned)gx < 512u);
        float a0 = 0.f, a1 = 0.f, a2 = 0.f;
        if (in) {
            int b = gy * 512 + gx;
            a0 = A[b]; a1 = A[262144 + b]; a2 = A[524288 + b];
        }
#pragma unroll
        for (int j = 0; j < 12; j++) {
            float t = in ? (wsm[36 + j] + wsm[j * 3] * a0 + wsm[j * 3 + 1] * a1
                            + wsm[j * 3 + 2] * a2)
                         : 0.f;
            p[j][i] = t;
        }
    }
    __syncthreads();

#pragma unroll
    for (int it = 0; it < 2; it++) {
        int pl = tid + it * 256;
        int ly = pl >> 5, lx = pl & 31;
        float z[12];
#pragma unroll
        for (int j = 0; j < 12; j++) {
            const float* dw = &wsm[48 + j * 9];
            const float* pr = &p[j][ly * 34 + lx];
            z[j] = wsm[156 + j]
                 + dw[0] * pr[0]  + dw[1] * pr[1]  + dw[2] * pr[2]
                 + dw[3] * pr[34] + dw[4] * pr[35] + dw[5] * pr[36]
                 + dw[6] * pr[68] + dw[7] * pr[69] + dw[8] * pr[70];
        }
        float g[6];
#pragma unroll
        for (int j = 0; j < 6; j++) {
            float xx = z[j];
            g[j] = 0.5f * xx * (1.f + erff(xx * 0.70710678118f)) * z[6 + j];
        }
        int b = (y0 + ly) * 512 + (x0 + lx);
#pragma unroll
        for (int co = 0; co < 3; co++) {
            float r = wsm[186 + co];
#pragma unroll
            for (int j = 0; j < 6; j++) r = fmaf(wsm[168 + co * 6 + j], g[j], r);
            r += x[co * 262144 + b];             // residual
            out[co * 262144 + b] = r;
        }
    }
}

// ---------------------------------------------------------------------------
extern "C" void kernel_launch(void* const* d_in, const int* in_sizes, int n_in,
                              void* d_out, int out_size, void* d_ws, size_t ws_size,
                              hipStream_t stream) {
    float* ws = (float*)d_ws;
    float* out = (float*)d_out;
    const float* x   = (const float*)d_in[0];
    const float* cw  = (const float*)d_in[1];
    const float* cb  = (const float*)d_in[2];
    const float* qw1 = (const float*)d_in[3];
    const float* kw1 = (const float*)d_in[7];
    const float* vw1 = (const float*)d_in[11];
    const float* temp= (const float*)d_in[15];

    MlpPtrs mp;
    mp.b1[0] = (const float*)d_in[4];  mp.w2[0] = (const float*)d_in[5];  mp.b2[0] = (const float*)d_in[6];
    mp.b1[1] = (const float*)d_in[8];  mp.w2[1] = (const float*)d_in[9];  mp.b2[1] = (const float*)d_in[10];
    mp.b1[2] = (const float*)d_in[12]; mp.w2[2] = (const float*)d_in[13]; mp.b2[2] = (const float*)d_in[14];

    FfnPtrs fp;
    for (int i = 0; i < 6; i++) fp.p[i] = (const float*)d_in[16 + i];

    k_prep<<<62, 256, 0, stream>>>(qw1, kw1, vw1, mp, ws);
    k_corr<<<dim3(64, 3, 3), 256, 0, stream>>>(x, qw1, kw1, vw1, ws);
    k_mlp <<<dim3(384, 3), 256, 0, stream>>>(cw, cb, mp, ws);
    k_attn<<<dim3(24, 4), 512, 0, stream>>>(temp, ws);
    k_ffn <<<dim3(16, 32), 256, 0, stream>>>(ws, x, fp, out);
}

// Round 3
// 205.511 us; speedup vs baseline: 1.5970x; 1.0799x over previous
//
#include <hip/hip_runtime.h>
#include <math.h>

// ---------------------------------------------------------------------------
// Restormer block, B=1 DIM=3 NC=512 HEADS=2 -> CT=768, NT=32, HID=6. f32 I/O.
//
// R16: stage-1 of the MLP (27-tap conv x w1 contraction) moved onto MFMA.
// k_corr scatters taps into GB2[v][n][h][k=ci*9+dy*3+dx] (f16, zero-prefilled
// by k_prep so h-edges and k=27..31 pads are exact zeros). New fused k_mlp:
// per block (32c x 4n x 512h): per 32-h chunk, stage-1 = 2x mfma 32x32x16_f16
// (cwB frags x GB2 frags) -> sigmoid -> bf16 y1 tile in swizzled LDS ->
// stage-2 = 2x mfma 32x32x16_bf16 vs prepacked w2 frags. No k-split.
// k_attn / k_ffn unchanged (offsets rebased).
// ---------------------------------------------------------------------------

__device__ __forceinline__ float sigm(float s) {
    return __builtin_amdgcn_rcpf(1.f + __expf(-s));
}

using bf16x8 = __attribute__((ext_vector_type(8))) short;     // 8 bf16 (4 VGPRs)
using f16x8  = __attribute__((ext_vector_type(8))) _Float16;  // 8 f16  (4 VGPRs)
using f32x16 = __attribute__((ext_vector_type(16))) float;

__device__ __forceinline__ unsigned short f2bf(float f) {
    union { __bf16 h; unsigned short s; } u;
    u.h = (__bf16)f;                    // HW cvt, RNE
    return u.s;
}
__device__ __forceinline__ unsigned short f2h(float f) {
    union { _Float16 h; unsigned short s; } u;
    u.h = (_Float16)f;                  // HW cvt, RNE
    return u.s;
}

// ---- f32 workspace layout (element offsets) -------------------------------
// GB2: tap tensor, f16. u16 index = ((v*32 + n)*512 + h)*32 + k,
//      k = ci*9 + dy*3 + dx (k=27..31 zero pad; h-edge dy slots stay zero).
static constexpr int OFF_GB  = 0;          // 1,572,864 u16 = 786,432 f32
static constexpr int OFF_S1  = 786432;     // [3v][32] column sums of w1 (96)
static constexpr int OFF_CWB = 786528;     // cw f16 pack [768c][32k] = 12288 f32
static constexpr int OFF_SC  = 798816;     // w2 bf16 B-frag pack [3v][32hc][64lane][uint4] = 24576 f32
static constexpr int OFF_QKV = 823392;     // ushort: Qb[4][768][256] | Kb | Vt[4][256][768] = 1179648 f32
static constexpr int OFF_ATT = 2003040;    // [4head][768][256] f32 == (3,512,512) flat
// total 2,789,472 floats = 11.2 MB

struct MlpPtrs {
    const float* b1[3];
    const float* w2[3];
    const float* b2[3];
};

// ---------------------------------------------------------------------------
// k_prep: zero-prefill GB2; S1[v][n] = sum_u w1v[u][n]; pack w2 into bf16
// B-fragments at OFF_SC; pack cw into f16 A-rows at OFF_CWB.
// grid 819 x 256 (196608 float4 zeros + 13056 task threads).
// ---------------------------------------------------------------------------
__global__ __launch_bounds__(256) void k_prep(const float* __restrict__ qw1,
                                              const float* __restrict__ kw1,
                                              const float* __restrict__ vw1,
                                              const float* __restrict__ cwp,
                                              MlpPtrs mp,
                                              float* __restrict__ ws) {
    int i = blockIdx.x * 256 + threadIdx.x;
    if (i < 196608) {                       // GB2 zero prefill (16B stores)
        ((float4*)ws)[i] = make_float4(0.f, 0.f, 0.f, 0.f);
        return;
    }
    int j = i - 196608;
    if (j < 6144) {                         // S1: 96 waves, shuffle-reduce
        int w = j >> 6, lane = j & 63;
        int v = w >> 5, n = w & 31;
        const float* w1p = (v == 0) ? qw1 : ((v == 1) ? kw1 : vw1);
        float s = 0.f;
#pragma unroll
        for (int k = 0; k < 8; k++) s += w1p[(lane + 64 * k) * 32 + n];
#pragma unroll
        for (int off = 32; off > 0; off >>= 1) s += __shfl_xor(s, off);
        if (lane == 0) ws[OFF_S1 + w] = s;
    } else if (j < 12288) {                 // w2 -> bf16 B-fragments
        int jj = j - 6144;                  // jj = v*2048 + hc*64 + lane
        int v = jj >> 11, r = jj & 2047;
        int hc = r >> 6, lane = r & 63;
        int o = lane & 31, half = lane >> 5;
        int H = hc * 16 + half * 8;
        const float* w2p = mp.w2[v];
        unsigned int d[4];
#pragma unroll
        for (int t = 0; t < 4; t++) {
            unsigned int lo = f2bf(w2p[(H + 2 * t) * 32 + o]);
            unsigned int hi = f2bf(w2p[(H + 2 * t + 1) * 32 + o]);
            d[t] = (hi << 16) | lo;
        }
        uint4* dst = (uint4*)(ws + OFF_SC);
        dst[jj] = make_uint4(d[0], d[1], d[2], d[3]);
    } else if (j < 13056) {                 // cw -> f16 A-rows [c][32k]
        int c = j - 12288;
        unsigned short* cwB = (unsigned short*)(ws + OFF_CWB);
#pragma unroll
        for (int k = 0; k < 32; k++)
            cwB[c * 32 + k] = (k < 27) ? f2h(cwp[c * 27 + k]) : (unsigned short)0;
    }
}

// ---------------------------------------------------------------------------
// k_corr: taps a_dx(ci, h_src, n) = sum_u x[ci][h_src][u] * w1v[u+1-dx][n],
// scattered into GB2 at h_out = h_src + 1 - dy for dy = 0,1,2.
// grid (64 hblk, 3 ci, 3 v), block 256 = 8 rows x 32 n.
// ---------------------------------------------------------------------------
__global__ __launch_bounds__(256) void k_corr(const float* __restrict__ x,
                                              const float* __restrict__ qw1,
                                              const float* __restrict__ kw1,
                                              const float* __restrict__ vw1,
                                              float* __restrict__ ws) {
    const int h0 = blockIdx.x * 8, ci = blockIdx.y, v = blockIdx.z;
    const int tid = threadIdx.x;
    __shared__ __align__(16) float ws1t[32 * 516];

    const float* w1f = (v == 0) ? qw1 : ((v == 1) ? kw1 : vw1);
    for (int i = tid; i < 4096; i += 256) {       // transpose-stage w1
        int n_ = i & 31, u = (i >> 5) * 4;
        float a = w1f[(u + 0) * 32 + n_];
        float b = w1f[(u + 1) * 32 + n_];
        float c = w1f[(u + 2) * 32 + n_];
        float d = w1f[(u + 3) * 32 + n_];
        *(float4*)&ws1t[n_ * 516 + u] = make_float4(a, b, c, d);
    }
    if (tid < 32) *(float4*)&ws1t[tid * 516 + 512] = make_float4(0.f, 0.f, 0.f, 0.f);
    __syncthreads();

    const int hp = tid >> 5, n = tid & 31;
    const float* xrow = x + ci * 262144 + (h0 + hp) * 512;
    float a0 = 0.f, a1 = 0.f, a2 = 0.f, pq = 0.f;
    float4 cq = *(float4*)&ws1t[n * 516];
#pragma unroll 4
    for (int k = 0; k < 128; k++) {
        float4 nq = *(float4*)&ws1t[n * 516 + 4 * k + 4];
        float4 x4 = *(const float4*)&xrow[4 * k];
        a1 = fmaf(x4.x, cq.x, a1); a1 = fmaf(x4.y, cq.y, a1);
        a1 = fmaf(x4.z, cq.z, a1); a1 = fmaf(x4.w, cq.w, a1);
        a0 = fmaf(x4.x, cq.y, a0); a0 = fmaf(x4.y, cq.z, a0);
        a0 = fmaf(x4.z, cq.w, a0); a0 = fmaf(x4.w, nq.x, a0);
        a2 = fmaf(x4.x, pq,   a2); a2 = fmaf(x4.y, cq.x, a2);
        a2 = fmaf(x4.z, cq.y, a2); a2 = fmaf(x4.w, cq.z, a2);
        pq = cq.w; cq = nq;
    }
    const unsigned short t0 = f2h(a0), t1 = f2h(a1), t2 = f2h(a2);
    unsigned short* gb = (unsigned short*)ws;          // OFF_GB = 0
    const int h = h0 + hp;                              // h_src
    const size_t basen = ((size_t)(v * 32 + n) * 512) * 32 + (size_t)ci * 9;
    if (h <= 510) {                     // dy=0: h_out = h+1, k += 0..2
        size_t b = basen + (size_t)(h + 1) * 32;
        gb[b] = t0; gb[b + 1] = t1; gb[b + 2] = t2;
    }
    {                                   // dy=1: h_out = h, k += 3..5
        size_t b = basen + (size_t)h * 32 + 3;
        gb[b] = t0; gb[b + 1] = t1; gb[b + 2] = t2;
    }
    if (h >= 1) {                       // dy=2: h_out = h-1, k += 6..8
        size_t b = basen + (size_t)(h - 1) * 32 + 6;
        gb[b] = t0; gb[b + 1] = t1; gb[b + 2] = t2;
    }
}

// ---------------------------------------------------------------------------
// k_mlp: fused MFMA stage-1 + stage-2. Block = 32 c x 4 n x all 512 h,
// 256 thr = 4 waves (wave w owns n_l = w in stage-1, M-tile w in stage-2).
// Per 32-h chunk: stage-1 C[c][h] = cwB x GB2 (2x mfma f16, f32 acc) ->
// +base -> sigmoid -> bf16 into swizzled LDS tile [128 row][32 h] ->
// barrier -> stage-2 acc[(c,n)][o] += y1 x w2 (2x mfma bf16) -> barrier.
// Epilogue: sigmoid(acc + b2) -> bf16 Q,K and V^T (same mapping as R15).
// grid (24 ctile, 8 nquad, 3 v) = 576 blocks.
// ---------------------------------------------------------------------------
__global__ __launch_bounds__(256) void k_mlp(const float* __restrict__ cbp,
                                             MlpPtrs mp, float* __restrict__ ws) {
    const int v = blockIdx.z;
    const int c0 = blockIdx.x * 32;
    const int n0 = blockIdx.y * 4;
    const int tid = threadIdx.x;
    const int w = tid >> 6, lane = tid & 63;
    const int m = lane & 31, half = lane >> 5;

    __shared__ __align__(16) unsigned short y1t[128 * 32];   // 8 KB, swizzled

    // stage-1 A: cw f16 frags, row = c_l = m, K split in two frags
    const unsigned short* cwB = (const unsigned short*)(ws + OFF_CWB);
    const f16x8 afA0 = *(const f16x8*)(cwB + (c0 + m) * 32 + half * 8);
    const f16x8 afA1 = *(const f16x8*)(cwB + (c0 + m) * 32 + 16 + half * 8);

    // stage-2 B: w2 bf16 frags
    const uint4* w2pk = (const uint4*)(ws + OFF_SC) + (size_t)v * 2048 + lane;

    int rowv[16];
#pragma unroll
    for (int r = 0; r < 16; r++) rowv[r] = (r & 3) + 8 * (r >> 2) + 4 * half;

    const int nl = w;                                // this wave's n (stage-1)
    const float b1n = mp.b1[v][n0 + nl];
    const float s1n = ws[OFF_S1 + v * 32 + n0 + nl];
    float bases[16];
#pragma unroll
    for (int r = 0; r < 16; r++)
        bases[r] = b1n + cbp[c0 + rowv[r]] * s1n;

    const unsigned short* gbv = (const unsigned short*)ws
        + ((size_t)(v * 32 + n0 + nl) * 512) * 32;

    f32x16 acc;
#pragma unroll
    for (int r = 0; r < 16; r++) acc[r] = 0.f;

    // prefetch chunk 0 B-frags
    f16x8 nb0 = *(const f16x8*)(gbv + (size_t)m * 32 + half * 8);
    f16x8 nb1 = *(const f16x8*)(gbv + (size_t)m * 32 + 16 + half * 8);

    for (int t = 0; t < 16; t++) {
        const f16x8 cb0 = nb0, cb1 = nb1;
        if (t < 15) {                                // prefetch next chunk
            const size_t nb = (size_t)((t + 1) * 32 + m) * 32;
            nb0 = *(const f16x8*)(gbv + nb + half * 8);
            nb1 = *(const f16x8*)(gbv + nb + 16 + half * 8);
        }
        f32x16 s1a;
#pragma unroll
        for (int r = 0; r < 16; r++) s1a[r] = 0.f;
        s1a = __builtin_amdgcn_mfma_f32_32x32x16_f16(afA0, cb0, s1a, 0, 0, 0);
        s1a = __builtin_amdgcn_mfma_f32_32x32x16_f16(afA1, cb1, s1a, 0, 0, 0);

        // sigmoid + swizzled LDS write: row = c_l*4 + nl, col = h_l = m
#pragma unroll
        for (int r = 0; r < 16; r++) {
            float y = sigm(s1a[r] + bases[r]);
            int row = rowv[r] * 4 + nl;
            int byte = (row * 64 + m * 2) ^ ((row & 7) << 4);
            *(unsigned short*)((char*)y1t + byte) = f2bf(y);
        }
        __syncthreads();

        // stage-2: M-tile w, rows w*32 + m
        {
            const int row = w * 32 + m;
            const int swz = (row & 7) << 4;
            const int byte0 = (row * 64 + half * 16) ^ swz;
            const int byte1 = (row * 64 + 32 + half * 16) ^ swz;
            bf16x8 a0 = *(const bf16x8*)((char*)y1t + byte0);
            bf16x8 a1 = *(const bf16x8*)((char*)y1t + byte1);
            union { uint4 u; bf16x8 b; } bw0, bw1;
            bw0.u = w2pk[(t * 2) * 64];
            bw1.u = w2pk[(t * 2 + 1) * 64];
            acc = __builtin_amdgcn_mfma_f32_32x32x16_bf16(a0, bw0.b, acc, 0, 0, 0);
            acc = __builtin_amdgcn_mfma_f32_32x32x16_bf16(a1, bw1.b, acc, 0, 0, 0);
        }
        __syncthreads();
    }

    // epilogue
    const float b2v = mp.b2[v][m];                   // o = m
    unsigned short* uq = (unsigned short*)(ws + OFF_QKV);
#pragma unroll
    for (int r = 0; r < 16; r++) {
        int rowg = w * 32 + rowv[r];
        int c  = c0 + (rowg >> 2);
        int ny = n0 + (rowg & 3);
        float mm = sigm(acc[r] + b2v);
        int head = ((m & 1) << 1) | (ny & 1);
        int sidx = ((m >> 1) << 4) | (ny >> 1);
        if (v < 2)  uq[v * 786432 + head * 196608 + c * 256 + sidx] = f2bf(mm);
        else        uq[2 * 786432 + head * 196608 + sidx * 768 + c] = f2bf(mm);
    }
}

// ---------------------------------------------------------------------------
// k_attn: fused QK^T * temp -> softmax -> @V for one (head, 32-row band).
// Block 512 = 8 waves. grid (24 iband, 4 head). (unchanged from R13/R15)
// ---------------------------------------------------------------------------
__global__ __launch_bounds__(512) void k_attn(const float* __restrict__ tempr,
                                              float* __restrict__ ws) {
    const unsigned short* uq = (const unsigned short*)(ws + OFF_QKV);
    const int head = blockIdx.y;
    const int i0 = blockIdx.x * 32;
    const int w = threadIdx.x >> 6, lane = threadIdx.x & 63;
    const int m = lane & 31, half = lane >> 5;

    __shared__ __align__(16) unsigned short ap[32][776];   // attn bf16, padded
    __shared__ float mxw[8][32];
    __shared__ float smw[8][32];
    __shared__ float gmx[32];
    __shared__ float gsm[32];

    const float temp = tempr[head];
    const unsigned short* Qp = uq + head * 196608 + (i0 + m) * 256 + half * 8;

    // ---- phase 1: QK^T for 3 j-tiles --------------------------------------
    f32x16 acc[3];
#pragma unroll
    for (int t = 0; t < 3; t++)
#pragma unroll
        for (int r = 0; r < 16; r++) acc[t][r] = 0.f;
#pragma unroll
    for (int t = 0; t < 3; t++) {
        const int j0 = (w * 3 + t) * 32;
        const unsigned short* Kp = uq + 786432 + head * 196608 + (j0 + m) * 256 + half * 8;
#pragma unroll
        for (int kk = 0; kk < 16; kk++) {
            bf16x8 af = *(const bf16x8*)(Qp + kk * 16);
            bf16x8 bf = *(const bf16x8*)(Kp + kk * 16);
            acc[t] = __builtin_amdgcn_mfma_f32_32x32x16_bf16(af, bf, acc[t], 0, 0, 0);
        }
    }
#pragma unroll
    for (int t = 0; t < 3; t++)
#pragma unroll
        for (int r = 0; r < 16; r++) acc[t][r] *= temp;

    // ---- phase 2: block softmax -------------------------------------------
    int rowv[16];
#pragma unroll
    for (int r = 0; r < 16; r++) rowv[r] = (r & 3) + 8 * (r >> 2) + 4 * half;

    float rmx[16];
#pragma unroll
    for (int r = 0; r < 16; r++)
        rmx[r] = fmaxf(fmaxf(acc[0][r], acc[1][r]), acc[2][r]);
#pragma unroll
    for (int off = 16; off > 0; off >>= 1)
#pragma unroll
        for (int r = 0; r < 16; r++) rmx[r] = fmaxf(rmx[r], __shfl_xor(rmx[r], off));
    if (m == 0) {
#pragma unroll
        for (int r = 0; r < 16; r++) mxw[w][rowv[r]] = rmx[r];
    }
    __syncthreads();
    if (threadIdx.x < 32) {
        float g = mxw[0][threadIdx.x];
#pragma unroll
        for (int ww = 1; ww < 8; ww++) g = fmaxf(g, mxw[ww][threadIdx.x]);
        gmx[threadIdx.x] = g;
    }
    __syncthreads();

    float rsm[16];
#pragma unroll
    for (int r = 0; r < 16; r++) {
        float gm = gmx[rowv[r]];
        float e0 = __expf(acc[0][r] - gm);
        float e1 = __expf(acc[1][r] - gm);
        float e2 = __expf(acc[2][r] - gm);
        acc[0][r] = e0; acc[1][r] = e1; acc[2][r] = e2;
        rsm[r] = (e0 + e1) + e2;
    }
#pragma unroll
    for (int off = 16; off > 0; off >>= 1)
#pragma unroll
        for (int r = 0; r < 16; r++) rsm[r] += __shfl_xor(rsm[r], off);
    if (m == 0) {
#pragma unroll
        for (int r = 0; r < 16; r++) smw[w][rowv[r]] = rsm[r];
    }
    __syncthreads();
    if (threadIdx.x < 32) {
        float g = smw[0][threadIdx.x];
#pragma unroll
        for (int ww = 1; ww < 8; ww++) g += smw[ww][threadIdx.x];
        gsm[threadIdx.x] = g;
    }
    __syncthreads();

    // ---- phase 3: attn bf16 -> LDS, then PV --------------------------------
#pragma unroll
    for (int r = 0; r < 16; r++) {
        float inv = __builtin_amdgcn_rcpf(gsm[rowv[r]]);
#pragma unroll
        for (int t = 0; t < 3; t++)
            ap[rowv[r]][(w * 3 + t) * 32 + m] = f2bf(acc[t][r] * inv);
    }
    __syncthreads();

    const int s0 = w * 32;
    const unsigned short* Vp = uq + 2 * 786432 + head * 196608 + (s0 + m) * 768 + half * 8;
    f32x16 po;
#pragma unroll
    for (int r = 0; r < 16; r++) po[r] = 0.f;
#pragma unroll
    for (int kk = 0; kk < 48; kk++) {
        bf16x8 af = *(const bf16x8*)&ap[m][half * 8 + kk * 16];
        bf16x8 bf = *(const bf16x8*)(Vp + kk * 16);
        po = __builtin_amdgcn_mfma_f32_32x32x16_bf16(af, bf, po, 0, 0, 0);
    }
    float* O = ws + OFF_ATT + head * 196608;
#pragma unroll
    for (int r = 0; r < 16; r++) {
        O[(i0 + rowv[r]) * 256 + s0 + m] = po[r];
    }
}

// ---------------------------------------------------------------------------
// k_ffn: fused pointwise(3->12) + dwconv3x3 + gelu-gate + pointwise(6->3)
// + residual, f32 store. 32x16 pixel tiles (512 blocks), 34x18 halo in LDS.
// ---------------------------------------------------------------------------
struct FfnPtrs { const float* p[6]; };  // pi_w, pi_b, dw_w, dw_b, po_w, po_b

__global__ __launch_bounds__(256) void k_ffn(const float* __restrict__ ws,
                                             const float* __restrict__ x,
                                             FfnPtrs fp,
                                             float* __restrict__ out) {
    const int x0 = blockIdx.x * 32, y0 = blockIdx.y * 16;
    __shared__ float wsm[192];
    __shared__ float p[12][612];
    const int tid = threadIdx.x;
    if (tid < 36)       wsm[tid] = fp.p[0][tid];          // pi_w (12,3)
    else if (tid < 48)  wsm[tid] = fp.p[1][tid - 36];     // pi_b (12)
    else if (tid < 156) wsm[tid] = fp.p[2][tid - 48];     // dw_w (12,9)
    else if (tid < 168) wsm[tid] = fp.p[3][tid - 156];    // dw_b (12)
    else if (tid < 186) wsm[tid] = fp.p[4][tid - 168];    // po_w (3,6)
    else if (tid < 189) wsm[tid] = fp.p[5][tid - 186];    // po_b (3)
    __syncthreads();

    const float* A = ws + OFF_ATT;
    for (int i = tid; i < 612; i += 256) {
        int py = i / 34, px = i % 34;
        int gy = y0 + py - 1, gx = x0 + px - 1;
        bool in = ((unsigned)gy < 512u) && ((unsigned)gx < 512u);
        float a0 = 0.f, a1 = 0.f, a2 = 0.f;
        if (in) {
            int b = gy * 512 + gx;
            a0 = A[b]; a1 = A[262144 + b]; a2 = A[524288 + b];
        }
#pragma unroll
        for (int j = 0; j < 12; j++) {
            float t = in ? (wsm[36 + j] + wsm[j * 3] * a0 + wsm[j * 3 + 1] * a1
                            + wsm[j * 3 + 2] * a2)
                         : 0.f;
            p[j][i] = t;
        }
    }
    __syncthreads();

#pragma unroll
    for (int it = 0; it < 2; it++) {
        int pl = tid + it * 256;
        int ly = pl >> 5, lx = pl & 31;
        float z[12];
#pragma unroll
        for (int j = 0; j < 12; j++) {
            const float* dw = &wsm[48 + j * 9];
            const float* pr = &p[j][ly * 34 + lx];
            z[j] = wsm[156 + j]
                 + dw[0] * pr[0]  + dw[1] * pr[1]  + dw[2] * pr[2]
                 + dw[3] * pr[34] + dw[4] * pr[35] + dw[5] * pr[36]
                 + dw[6] * pr[68] + dw[7] * pr[69] + dw[8] * pr[70];
        }
        float g[6];
#pragma unroll
        for (int j = 0; j < 6; j++) {
            float xx = z[j];
            g[j] = 0.5f * xx * (1.f + erff(xx * 0.70710678118f)) * z[6 + j];
        }
        int b = (y0 + ly) * 512 + (x0 + lx);
#pragma unroll
        for (int co = 0; co < 3; co++) {
            float r = wsm[186 + co];
#pragma unroll
            for (int j = 0; j < 6; j++) r = fmaf(wsm[168 + co * 6 + j], g[j], r);
            r += x[co * 262144 + b];             // residual
            out[co * 262144 + b] = r;
        }
    }
}

// ---------------------------------------------------------------------------
extern "C" void kernel_launch(void* const* d_in, const int* in_sizes, int n_in,
                              void* d_out, int out_size, void* d_ws, size_t ws_size,
                              hipStream_t stream) {
    float* ws = (float*)d_ws;
    float* out = (float*)d_out;
    const float* x   = (const float*)d_in[0];
    const float* cw  = (const float*)d_in[1];
    const float* cb  = (const float*)d_in[2];
    const float* qw1 = (const float*)d_in[3];
    const float* kw1 = (const float*)d_in[7];
    const float* vw1 = (const float*)d_in[11];
    const float* temp= (const float*)d_in[15];

    MlpPtrs mp;
    mp.b1[0] = (const float*)d_in[4];  mp.w2[0] = (const float*)d_in[5];  mp.b2[0] = (const float*)d_in[6];
    mp.b1[1] = (const float*)d_in[8];  mp.w2[1] = (const float*)d_in[9];  mp.b2[1] = (const float*)d_in[10];
    mp.b1[2] = (const float*)d_in[12]; mp.w2[2] = (const float*)d_in[13]; mp.b2[2] = (const float*)d_in[14];

    FfnPtrs fp;
    for (int i = 0; i < 6; i++) fp.p[i] = (const float*)d_in[16 + i];

    k_prep<<<819, 256, 0, stream>>>(qw1, kw1, vw1, cw, mp, ws);
    k_corr<<<dim3(64, 3, 3), 256, 0, stream>>>(x, qw1, kw1, vw1, ws);
    k_mlp <<<dim3(24, 8, 3), 256, 0, stream>>>(cb, mp, ws);
    k_attn<<<dim3(24, 4), 512, 0, stream>>>(temp, ws);
    k_ffn <<<dim3(16, 32), 256, 0, stream>>>(ws, x, fp, out);
}